// Round 20
// baseline (125.551 us; speedup 1.0000x reference)
//
#include <hip/hip_runtime.h>

#define B_ 2
#define S_ 2048
#define D_ 1024
#define H_ 16
#define DK_ 64

typedef float f32x4 __attribute__((ext_vector_type(4)));
typedef float f32x16 __attribute__((ext_vector_type(16)));
typedef short bf16x8 __attribute__((ext_vector_type(8)));

static __device__ __forceinline__ unsigned short f2bf(float f) {
  unsigned u = __float_as_uint(f);
  unsigned r = (u + 0x7FFFu + ((u >> 16) & 1u)) >> 16;
  return (unsigned short)r;
}

static __device__ __forceinline__ unsigned cvtpk_bf16(float lo, float hi) {
  unsigned r;
  asm("v_cvt_pk_bf16_f32 %0, %1, %2" : "=v"(r) : "v"(lo), "v"(hi));
  return r;
}

static __device__ __forceinline__ void load16_lds(const void* g, void* lds) {
  __builtin_amdgcn_global_load_lds(
      (const __attribute__((address_space(1))) unsigned int*)g,
      (__attribute__((address_space(3))) unsigned int*)lds, 16, 0, 0);
}

// gather 8 consecutive C-rows of this lane's owned column from crow-scattered
// accumulator regs p[0..7] -> packed bf16 A-frag k-slice.
// permlane32_swap: swap(dst=x, src=y): x' = {x.lo32lanes, y.lo32lanes},
// y' = {x.hi32lanes, y.hi32lanes}. VALIDATED on HW in r13-r19.
static __device__ __forceinline__ bf16x8 make_pa8(const float* p, int hi) {
  unsigned x1 = cvtpk_bf16(p[0], p[1]);
  unsigned x2 = cvtpk_bf16(p[2], p[3]);
  unsigned y1 = cvtpk_bf16(p[4], p[5]);
  unsigned y2 = cvtpk_bf16(p[6], p[7]);
  asm("v_permlane32_swap_b32 %0, %1" : "+v"(x1), "+v"(y1));
  asm("v_permlane32_swap_b32 %0, %1" : "+v"(x2), "+v"(y2));
  union {
    unsigned u[4];
    bf16x8 v;
  } pa;
  pa.u[0] = x1;
  pa.u[1] = x2;
  pa.u[2] = y1;
  pa.u[3] = y2;
  (void)hi;
  return pa.v;
}

static __device__ __forceinline__ float tanh_fast(float x) {
  float xc = fminf(fmaxf(x, -9.0f), 9.0f);
  float e = exp2f(xc * 2.88539008177792681472f);  // 2*log2(e)
  return (e - 1.0f) / (e + 1.0f);
}

// ---------------------------------------------------------------------------
// Kernel 1: fused MFMA quantum transform for q, k, v (z=0..2) + Wo transpose
// (z=3). 256 threads. Weight fragments loaded once per block; x rows staged
// COALESCED through LDS (fixes the 4KB-stride uncoalesced x gather).
// ---------------------------------------------------------------------------
__global__ __launch_bounds__(256) void quantum_fused(
    const float* __restrict__ xq, const float* __restrict__ xk,
    const float* __restrict__ xv,
    const float* __restrict__ Wq1, const float* __restrict__ bq1,
    const float* __restrict__ Wq2, const float* __restrict__ bq2,
    const float* __restrict__ Wk1, const float* __restrict__ bk1,
    const float* __restrict__ Wk2, const float* __restrict__ bk2,
    const float* __restrict__ Wv1, const float* __restrict__ bv1,
    const float* __restrict__ Wv2, const float* __restrict__ bv2,
    const float* __restrict__ Wo, unsigned short* __restrict__ WoT,
    unsigned short* __restrict__ qhb, unsigned short* __restrict__ khb,
    unsigned short* __restrict__ vtb, float qscale) {
  __shared__ float tt[64][65];
  __shared__ __align__(16) float xs[128][64];  // 32KB: one 128-row x chunk

  const int tid = threadIdx.x;

  if (blockIdx.z == 3) {
    const int bx = blockIdx.x * 2 + (blockIdx.y & 1);
    const int by = blockIdx.y >> 1;
    if (by >= 16) return;
    const int k0 = bx * 64, n0 = by * 64;
    const int r = tid >> 4, c4 = tid & 15;
#pragma unroll
    for (int i = 0; i < 4; ++i) {
      float4 v = *(const float4*)&Wo[(size_t)(k0 + r + 16 * i) * D_ + n0 + c4 * 4];
      tt[r + 16 * i][c4 * 4 + 0] = v.x;
      tt[r + 16 * i][c4 * 4 + 1] = v.y;
      tt[r + 16 * i][c4 * 4 + 2] = v.z;
      tt[r + 16 * i][c4 * 4 + 3] = v.w;
    }
    __syncthreads();
    const int n = tid >> 2, kc = tid & 3;
    union {
      unsigned short u[16];
      uint4 v[2];
    } pk;
#pragma unroll
    for (int j = 0; j < 16; ++j) pk.u[j] = f2bf(tt[kc * 16 + j][n]);
    unsigned short* op = WoT + (size_t)(n0 + n) * D_ + k0 + kc * 16;
    *(uint4*)op = pk.v[0];
    *(uint4*)(op + 8) = pk.v[1];
    return;
  }

  const int w = tid >> 6;
  const int l = tid & 63;
  const int lq = l & 31;
  const int hi = l >> 5;
  const int bh = blockIdx.y;
  const int b = bh >> 4, h = bh & 15;

  const float* x;
  const float* W1;
  const float* b1;
  const float* W2;
  const float* b2;
  unsigned short* outp;
  float scale = 1.0f;
  int vmode = 0;
  if (blockIdx.z == 0) {
    x = xq; W1 = Wq1; b1 = bq1; W2 = Wq2; b2 = bq2; outp = qhb;
    scale = qscale;
  } else if (blockIdx.z == 1) {
    x = xk; W1 = Wk1; b1 = bk1; W2 = Wk2; b2 = bk2; outp = khb;
  } else {
    x = xv; W1 = Wv1; b1 = bv1; W2 = Wv2; b2 = bv2; outp = vtb;
    vmode = 1;
  }

  // ---- weight fragments: loaded once per block ----
  bf16x8 w1f[2][4];
#pragma unroll
  for (int ca = 0; ca < 2; ++ca)
#pragma unroll
    for (int kc = 0; kc < 4; ++kc) {
      const float* wp = W1 + (size_t)(kc * 16 + hi * 8) * 64 + ca * 32 + lq;
      union {
        unsigned u[4];
        bf16x8 v;
      } ww;
#pragma unroll
      for (int jj = 0; jj < 4; ++jj)
        ww.u[jj] = cvtpk_bf16(wp[(2 * jj) * 64], wp[(2 * jj + 1) * 64]);
      w1f[ca][kc] = ww.v;
    }

  bf16x8 w2f[2][4];
#pragma unroll
  for (int nb = 0; nb < 2; ++nb)
#pragma unroll
    for (int kc = 0; kc < 4; ++kc) {
      const float* wp = W2 + (size_t)(kc * 16 + hi * 8) * 64 + nb * 32 + lq;
      union {
        unsigned u[4];
        bf16x8 v;
      } ww;
#pragma unroll
      for (int jj = 0; jj < 4; ++jj)
        ww.u[jj] = cvtpk_bf16(wp[(2 * jj) * 64], wp[(2 * jj + 1) * 64]);
      w2f[nb][kc] = ww.v;
    }

  float b1r[2][16], b2r[2][16];
#pragma unroll
  for (int ca = 0; ca < 2; ++ca)
#pragma unroll
    for (int r = 0; r < 16; ++r) {
      b1r[ca][r] = b1[ca * 32 + (r & 3) + 8 * (r >> 2) + 4 * hi];
      b2r[ca][r] = b2[ca * 32 + (r & 3) + 8 * (r >> 2) + 4 * hi];
    }

  // staging roles for x: round j covers rows j*16 + (tid>>4), col16 = tid&15
  const int xrow_s = tid >> 4;   // 0..15
  const int xcol16 = tid & 15;   // 16B unit within 256B row

  for (int chunk = 0; chunk < 2; ++chunk) {
    const int sbase = blockIdx.x * 256 + chunk * 128;

    // ---- coalesced x staging: 128 rows x 256B, linear LDS dest ----
    __syncthreads();  // previous chunk's xs reads complete
#pragma unroll
    for (int j = 0; j < 8; ++j) {
      const int row = j * 16 + xrow_s;
      load16_lds(x + (((size_t)b * S_ + sbase + row) * H_ + h) * DK_ + xcol16 * 4,
                 (char*)&xs[0][0] + (size_t)row * 256 + xcol16 * 16);
    }
    __syncthreads();  // gload_lds drained (implicit vmcnt at barrier)

    const int s0w = sbase + w * 32;
    const float* xrow = &xs[w * 32 + lq][0];
    bf16x8 xf[4];
#pragma unroll
    for (int kc = 0; kc < 4; ++kc) {
      float4 f0 = *(const float4*)(xrow + kc * 16 + hi * 8);
      float4 f1 = *(const float4*)(xrow + kc * 16 + hi * 8 + 4);
      union {
        unsigned u[4];
        bf16x8 v;
      } xx;
      xx.u[0] = cvtpk_bf16(f0.x, f0.y);
      xx.u[1] = cvtpk_bf16(f0.z, f0.w);
      xx.u[2] = cvtpk_bf16(f1.x, f1.y);
      xx.u[3] = cvtpk_bf16(f1.z, f1.w);
      xf[kc] = xx.v;
    }

    f32x16 acc1[2];
#pragma unroll
    for (int ca = 0; ca < 2; ++ca)
#pragma unroll
      for (int r = 0; r < 16; ++r) acc1[ca][r] = b1r[ca][r];
#pragma unroll
    for (int kc = 0; kc < 4; ++kc) {
      acc1[0] = __builtin_amdgcn_mfma_f32_32x32x16_bf16(w1f[0][kc], xf[kc], acc1[0], 0, 0, 0);
      acc1[1] = __builtin_amdgcn_mfma_f32_32x32x16_bf16(w1f[1][kc], xf[kc], acc1[1], 0, 0, 0);
    }

    float t0[16], t1[16];
#pragma unroll
    for (int r = 0; r < 16; ++r) {
      t0[r] = tanh_fast(acc1[0][r]);
      t1[r] = tanh_fast(acc1[1][r]);
    }

    bf16x8 af[4];
    af[0] = make_pa8(&t0[0], hi);
    af[1] = make_pa8(&t0[8], hi);
    af[2] = make_pa8(&t1[0], hi);
    af[3] = make_pa8(&t1[8], hi);

    f32x16 acc2[2];
#pragma unroll
    for (int nb = 0; nb < 2; ++nb)
#pragma unroll
      for (int r = 0; r < 16; ++r) acc2[nb][r] = b2r[nb][r];
#pragma unroll
    for (int kc = 0; kc < 4; ++kc) {
      acc2[0] = __builtin_amdgcn_mfma_f32_32x32x16_bf16(af[kc], w2f[0][kc], acc2[0], 0, 0, 0);
      acc2[1] = __builtin_amdgcn_mfma_f32_32x32x16_bf16(af[kc], w2f[1][kc], acc2[1], 0, 0, 0);
    }

    if (!vmode) {
#pragma unroll
      for (int nb = 0; nb < 2; ++nb)
#pragma unroll
        for (int r = 0; r < 16; ++r) {
          const int s = s0w + (r & 3) + 8 * (r >> 2) + 4 * hi;
          outp[((size_t)bh * S_ + s) * DK_ + nb * 32 + lq] =
              f2bf(acc2[nb][r] * scale);
        }
    } else {
#pragma unroll
      for (int nb = 0; nb < 2; ++nb) {
        float yv[16];
#pragma unroll
        for (int r = 0; r < 16; ++r) yv[r] = acc2[nb][r];
        const size_t rowb = ((size_t)bh * DK_ + nb * 32 + lq) * S_;
        *(bf16x8*)(outp + rowb + s0w + hi * 8) = make_pa8(&yv[0], hi);
        *(bf16x8*)(outp + rowb + s0w + 16 + hi * 8) = make_pa8(&yv[8], hi);
      }
    }
  }
}

// ---------------------------------------------------------------------------
// Kernel 2: MFMA flash attention (FROZEN, r19): QBLK=256, 8 q-group waves,
// exp2-direct softmax, l via ones-B MFMA, 3-buf depth-2 counted-vmcnt
// staging. grid (32 bh, 8 q-blocks), block 512, 48KB LDS.
// ---------------------------------------------------------------------------
__global__ __launch_bounds__(512, 2) void attn_kernel(
    const unsigned short* __restrict__ qhb,
    const unsigned short* __restrict__ khb,
    const unsigned short* __restrict__ vtb,
    unsigned short* __restrict__ ctxb) {
  __shared__ __align__(16) unsigned short kvbuf[3][2][64 * 64];  // 3-buf K/V

  const int tid = threadIdx.x;
  const int w = tid >> 6;  // 0..7 = q-group
  const int l = tid & 63;
  const int lq = l & 31;
  const int hi = l >> 5;
  const int bh = blockIdx.x;
  const int b = bh >> 4, h = bh & 15;
  const int q0 = blockIdx.y * 256 + w * 32;

  const unsigned short* qp = qhb + ((size_t)bh * S_ + q0 + lq) * DK_ + hi * 8;
  bf16x8 qf[4];
#pragma unroll
  for (int kc = 0; kc < 4; ++kc) qf[kc] = *(const bf16x8*)(qp + kc * 16);

  f32x16 o0 = {}, o1 = {};
  f32x16 lacc = {};

  union {
    unsigned u[4];
    bf16x8 v;
  } onesu;
  onesu.u[0] = 0x3F803F80u;
  onesu.u[1] = 0x3F803F80u;
  onesu.u[2] = 0x3F803F80u;
  onesu.u[3] = 0x3F803F80u;
  const bf16x8 ones = onesu.v;

  const unsigned short* kgbase = khb + (size_t)bh * S_ * DK_;
  const unsigned short* vgbase = vtb + (size_t)bh * DK_ * S_;
  const int srow = tid >> 3;
  const int sl8 = ((tid & 7) ^ (srow & 7)) * 8;

  const unsigned short* kp = kgbase + (size_t)srow * DK_ + sl8;
  const unsigned short* vp = vgbase + (size_t)srow * S_ + sl8;

#define STAGE(BUF)                                                            \
  {                                                                           \
    load16_lds(kp, (char*)kvbuf[BUF][0] + w * 1024);                          \
    load16_lds(vp, (char*)kvbuf[BUF][1] + w * 1024);                          \
    kp += 64 * DK_;                                                           \
    vp += 64;                                                                 \
  }

  STAGE(0)
  STAGE(1)

  for (int t = 0; t < 32; ++t) {
    if (t < 31) {
      asm volatile("s_waitcnt vmcnt(2)" ::: "memory");
    } else {
      asm volatile("s_waitcnt vmcnt(0)" ::: "memory");
    }
    __builtin_amdgcn_sched_barrier(0);
    __builtin_amdgcn_s_barrier();
    __builtin_amdgcn_sched_barrier(0);

    const int cur = t % 3;
    const char* ksP = (const char*)kvbuf[cur][0];
    const char* vsP = (const char*)kvbuf[cur][1];
    if (t < 30) STAGE((t + 2) % 3)

    f32x16 s0a = {}, s0b = {};
    __builtin_amdgcn_s_setprio(1);
#pragma unroll
    for (int kc = 0; kc < 4; ++kc) {
      const int so = ((kc * 2 + hi) ^ (lq & 7)) << 4;
      bf16x8 ka = *(const bf16x8*)(ksP + lq * 128 + so);
      bf16x8 kb = *(const bf16x8*)(ksP + (32 + lq) * 128 + so);
      s0a = __builtin_amdgcn_mfma_f32_32x32x16_bf16(ka, qf[kc], s0a, 0, 0, 0);
      s0b = __builtin_amdgcn_mfma_f32_32x32x16_bf16(kb, qf[kc], s0b, 0, 0, 0);
    }
    __builtin_amdgcn_s_setprio(0);

#pragma unroll
    for (int i = 0; i < 16; ++i) s0a[i] = exp2f(s0a[i]);
#pragma unroll
    for (int i = 0; i < 16; ++i) s0b[i] = exp2f(s0b[i]);

    float pv[8];
    __builtin_amdgcn_s_setprio(1);
#pragma unroll
    for (int kc = 0; kc < 4; ++kc) {
#pragma unroll
      for (int j = 0; j < 8; ++j) pv[j] = (kc < 2) ? s0a[(kc & 1) * 8 + j]
                                                   : s0b[(kc & 1) * 8 + j];
      bf16x8 pav = make_pa8(pv, hi);
      const int slot = kc * 2 + hi;
      bf16x8 v0 = *(const bf16x8*)(vsP + lq * 128 + ((slot ^ (lq & 7)) << 4));
      bf16x8 v1 = *(const bf16x8*)(vsP + (32 + lq) * 128 + ((slot ^ (lq & 7)) << 4));
      o0 = __builtin_amdgcn_mfma_f32_32x32x16_bf16(pav, v0, o0, 0, 0, 0);
      o1 = __builtin_amdgcn_mfma_f32_32x32x16_bf16(pav, v1, o1, 0, 0, 0);
      lacc = __builtin_amdgcn_mfma_f32_32x32x16_bf16(pav, ones, lacc, 0, 0, 0);
    }
    __builtin_amdgcn_s_setprio(0);
  }
#undef STAGE

#pragma unroll
  for (int r = 0; r < 16; ++r) {
    const int crow = ((r & 3) + 8 * (r >> 2)) + 4 * hi;
    const float li = 1.0f / lacc[r];
    const int qg = q0 + crow;
    const size_t base = ((size_t)b * S_ + qg) * D_ + h * DK_;
    ctxb[base + lq] = f2bf(o0[r] * li);
    ctxb[base + 32 + lq] = f2bf(o1[r] * li);
  }
}

// ---------------------------------------------------------------------------
// Kernel 3: out[4096,1024] = ctx_bf16 @ WoT^T + bo (FROZEN, r17).
// ---------------------------------------------------------------------------
__global__ __launch_bounds__(256) void out_gemm_mfma(
    const unsigned short* __restrict__ A,
    const unsigned short* __restrict__ BT,
    const float* __restrict__ bo, float* __restrict__ C) {
  __shared__ __align__(16) unsigned short As[2][128 * 64];
  __shared__ __align__(16) unsigned short Bs[2][64 * 64];

  const int tid = threadIdx.x;
  const int w = tid >> 6, l = tid & 63;
  const int ll = l & 15, lg = l >> 4;
  const int m0 = blockIdx.y * 128, n0 = blockIdx.x * 64;

  const int srow = l >> 3;
  const int sl8 = ((l & 7) ^ srow) * 8;

  f32x4 acc[2][4];
#pragma unroll
  for (int mt = 0; mt < 2; ++mt)
#pragma unroll
    for (int nt = 0; nt < 4; ++nt) acc[mt][nt] = (f32x4){0.f, 0.f, 0.f, 0.f};

#define STAGE_G(BUF, KT)                                                      \
  {                                                                           \
    const int k0e = (KT)*64;                                                  \
    _Pragma("unroll") for (int j = 0; j < 4; ++j) {                           \
      const int rowa = (w * 4 + j) * 8 + srow;                                \
      load16_lds(A + (size_t)(m0 + rowa) * D_ + k0e + sl8,                    \
                 (char*)As[BUF] + (w * 4 + j) * 1024);                        \
    }                                                                         \
    _Pragma("unroll") for (int j = 0; j < 2; ++j) {                           \
      const int rowb = (w * 2 + j) * 8 + srow;                                \
      load16_lds(BT + (size_t)(n0 + rowb) * D_ + k0e + sl8,                   \
                 (char*)Bs[BUF] + (w * 2 + j) * 1024);                        \
    }                                                                         \
  }

  STAGE_G(0, 0)
  __syncthreads();

  for (int kt = 0; kt < 16; ++kt) {
    const int cur = kt & 1;
    if (kt < 15) STAGE_G(cur ^ 1, kt + 1)

#pragma unroll
    for (int half = 0; half < 2; ++half) {
      bf16x8 af[2], bfr[4];
#pragma unroll
      for (int mt = 0; mt < 2; ++mt) {
        const int row = w * 32 + mt * 16 + ll;
        af[mt] = *(const bf16x8*)((const char*)As[cur] + row * 128 +
                                  (((half * 4 + lg) ^ (row & 7)) << 4));
      }
#pragma unroll
      for (int nt = 0; nt < 4; ++nt) {
        const int rowb = nt * 16 + ll;
        bfr[nt] = *(const bf16x8*)((const char*)Bs[cur] + rowb * 128 +
                                   (((half * 4 + lg) ^ (rowb & 7)) << 4));
      }
      __builtin_amdgcn_s_setprio(1);
#pragma unroll
      for (int mt = 0; mt < 2; ++mt)
#pragma unroll
        for (int nt = 0; nt < 4; ++nt)
          acc[mt][nt] = __builtin_amdgcn_mfma_f32_16x16x32_bf16(
              af[mt], bfr[nt], acc[mt][nt], 0, 0, 0);
      __builtin_amdgcn_s_setprio(0);
    }

    __syncthreads();
  }
#undef STAGE_G

#pragma unroll
  for (int nt = 0; nt < 4; ++nt) {
    const int col = n0 + nt * 16 + ll;
    const float bv = bo[col];
#pragma unroll
    for (int mt = 0; mt < 2; ++mt) {
      const int row0 = m0 + w * 32 + mt * 16 + lg * 4;
#pragma unroll
      for (int r = 0; r < 4; ++r)
        C[(size_t)(row0 + r) * D_ + col] = acc[mt][nt][r] + bv;
    }
  }
}

// ---------------------------------------------------------------------------
extern "C" void kernel_launch(void* const* d_in, const int* in_sizes, int n_in,
                              void* d_out, int out_size, void* d_ws,
                              size_t ws_size, hipStream_t stream) {
  const float* q = (const float*)d_in[0];
  const float* k = (const float*)d_in[1];
  const float* v = (const float*)d_in[2];
  const float* Wq1 = (const float*)d_in[3];
  const float* bq1 = (const float*)d_in[4];
  const float* Wq2 = (const float*)d_in[5];
  const float* bq2 = (const float*)d_in[6];
  const float* Wk1 = (const float*)d_in[7];
  const float* bk1 = (const float*)d_in[8];
  const float* Wk2 = (const float*)d_in[9];
  const float* bk2 = (const float*)d_in[10];
  const float* Wv1 = (const float*)d_in[11];
  const float* bv1 = (const float*)d_in[12];
  const float* Wv2 = (const float*)d_in[13];
  const float* bv2 = (const float*)d_in[14];
  const float* Wo = (const float*)d_in[15];
  const float* bo = (const float*)d_in[16];
  float* out = (float*)d_out;

  const size_t TEN = (size_t)B_ * H_ * S_ * DK_;  // 4,194,304 elements
  char* ws = (char*)d_ws;
  unsigned short* qhb = (unsigned short*)ws;              // bf16 [BH,S,DK]
  unsigned short* khb = (unsigned short*)(ws + TEN * 2);  // bf16 [BH,S,DK]
  unsigned short* vtb = (unsigned short*)(ws + TEN * 4);  // bf16 [BH,DK,S]
  unsigned short* ctxb = (unsigned short*)(ws + TEN * 6); // bf16 [B,S,D]
  unsigned short* wot = (unsigned short*)(ws + TEN * 8);  // bf16 [N,K] = Wo^T

  const float cs = 0.125f * 1.44269504088896340736f;  // 1/sqrt(64) * log2(e)
  quantum_fused<<<dim3(8, 32, 4), 256, 0, stream>>>(
      q, k, v, Wq1, bq1, Wq2, bq2, Wk1, bk1, Wk2, bk2, Wv1, bv1, Wv2, bv2,
      Wo, wot, qhb, khb, vtb, cs);

  attn_kernel<<<dim3(32, 8), 512, 0, stream>>>(qhb, khb, vtb, ctxb);

  out_gemm_mfma<<<dim3(16, 32), 256, 0, stream>>>(ctxb, wot, bo, out);
}

// Round 21
// 97.831 us; speedup vs baseline: 1.2833x; 1.2833x over previous
//
#include <hip/hip_runtime.h>

#define B_ 2
#define S_ 2048
#define D_ 1024
#define H_ 16
#define DK_ 64

typedef float f32x4 __attribute__((ext_vector_type(4)));
typedef float f32x16 __attribute__((ext_vector_type(16)));
typedef short bf16x8 __attribute__((ext_vector_type(8)));

static __device__ __forceinline__ unsigned short f2bf(float f) {
  unsigned u = __float_as_uint(f);
  unsigned r = (u + 0x7FFFu + ((u >> 16) & 1u)) >> 16;
  return (unsigned short)r;
}

static __device__ __forceinline__ unsigned cvtpk_bf16(float lo, float hi) {
  unsigned r;
  asm("v_cvt_pk_bf16_f32 %0, %1, %2" : "=v"(r) : "v"(lo), "v"(hi));
  return r;
}

static __device__ __forceinline__ void load16_lds(const void* g, void* lds) {
  __builtin_amdgcn_global_load_lds(
      (const __attribute__((address_space(1))) unsigned int*)g,
      (__attribute__((address_space(3))) unsigned int*)lds, 16, 0, 0);
}

// gather 8 consecutive C-rows of this lane's owned column from crow-scattered
// accumulator regs p[0..7] -> packed bf16 A-frag k-slice.
// permlane32_swap: swap(dst=x, src=y): x' = {x.lo32lanes, y.lo32lanes},
// y' = {x.hi32lanes, y.hi32lanes}. VALIDATED on HW in r13-r19.
static __device__ __forceinline__ bf16x8 make_pa8(const float* p, int hi) {
  unsigned x1 = cvtpk_bf16(p[0], p[1]);
  unsigned x2 = cvtpk_bf16(p[2], p[3]);
  unsigned y1 = cvtpk_bf16(p[4], p[5]);
  unsigned y2 = cvtpk_bf16(p[6], p[7]);
  asm("v_permlane32_swap_b32 %0, %1" : "+v"(x1), "+v"(y1));
  asm("v_permlane32_swap_b32 %0, %1" : "+v"(x2), "+v"(y2));
  union {
    unsigned u[4];
    bf16x8 v;
  } pa;
  pa.u[0] = x1;
  pa.u[1] = x2;
  pa.u[2] = y1;
  pa.u[3] = y2;
  (void)hi;
  return pa.v;
}

static __device__ __forceinline__ float tanh_fast(float x) {
  float xc = fminf(fmaxf(x, -9.0f), 9.0f);
  float e = exp2f(xc * 2.88539008177792681472f);  // 2*log2(e)
  return (e - 1.0f) / (e + 1.0f);
}

// ---------------------------------------------------------------------------
// Kernel 1: fused MFMA quantum transform for q, k, v (z=0..2) + Wo transpose
// (z=3). 256 threads. Weight fragments loaded once per block, reused over
// two 128-row chunks. Direct global x loads (r18-validated; the r20 x-LDS
// staging experiment regressed 8x on this kernel -- reverted).
// ---------------------------------------------------------------------------
__global__ __launch_bounds__(256) void quantum_fused(
    const float* __restrict__ xq, const float* __restrict__ xk,
    const float* __restrict__ xv,
    const float* __restrict__ Wq1, const float* __restrict__ bq1,
    const float* __restrict__ Wq2, const float* __restrict__ bq2,
    const float* __restrict__ Wk1, const float* __restrict__ bk1,
    const float* __restrict__ Wk2, const float* __restrict__ bk2,
    const float* __restrict__ Wv1, const float* __restrict__ bv1,
    const float* __restrict__ Wv2, const float* __restrict__ bv2,
    const float* __restrict__ Wo, unsigned short* __restrict__ WoT,
    unsigned short* __restrict__ qhb, unsigned short* __restrict__ khb,
    unsigned short* __restrict__ vtb, float qscale) {
  __shared__ float tt[64][65];

  const int tid = threadIdx.x;

  if (blockIdx.z == 3) {
    const int bx = blockIdx.x * 2 + (blockIdx.y & 1);
    const int by = blockIdx.y >> 1;
    if (by >= 16) return;
    const int k0 = bx * 64, n0 = by * 64;
    const int r = tid >> 4, c4 = tid & 15;
#pragma unroll
    for (int i = 0; i < 4; ++i) {
      float4 v = *(const float4*)&Wo[(size_t)(k0 + r + 16 * i) * D_ + n0 + c4 * 4];
      tt[r + 16 * i][c4 * 4 + 0] = v.x;
      tt[r + 16 * i][c4 * 4 + 1] = v.y;
      tt[r + 16 * i][c4 * 4 + 2] = v.z;
      tt[r + 16 * i][c4 * 4 + 3] = v.w;
    }
    __syncthreads();
    const int n = tid >> 2, kc = tid & 3;
    union {
      unsigned short u[16];
      uint4 v[2];
    } pk;
#pragma unroll
    for (int j = 0; j < 16; ++j) pk.u[j] = f2bf(tt[kc * 16 + j][n]);
    unsigned short* op = WoT + (size_t)(n0 + n) * D_ + k0 + kc * 16;
    *(uint4*)op = pk.v[0];
    *(uint4*)(op + 8) = pk.v[1];
    return;
  }

  const int w = tid >> 6;
  const int l = tid & 63;
  const int lq = l & 31;
  const int hi = l >> 5;
  const int bh = blockIdx.y;
  const int b = bh >> 4, h = bh & 15;

  const float* x;
  const float* W1;
  const float* b1;
  const float* W2;
  const float* b2;
  unsigned short* outp;
  float scale = 1.0f;
  int vmode = 0;
  if (blockIdx.z == 0) {
    x = xq; W1 = Wq1; b1 = bq1; W2 = Wq2; b2 = bq2; outp = qhb;
    scale = qscale;
  } else if (blockIdx.z == 1) {
    x = xk; W1 = Wk1; b1 = bk1; W2 = Wk2; b2 = bk2; outp = khb;
  } else {
    x = xv; W1 = Wv1; b1 = bv1; W2 = Wv2; b2 = bv2; outp = vtb;
    vmode = 1;
  }

  bf16x8 w1f[2][4];
#pragma unroll
  for (int ca = 0; ca < 2; ++ca)
#pragma unroll
    for (int kc = 0; kc < 4; ++kc) {
      const float* wp = W1 + (size_t)(kc * 16 + hi * 8) * 64 + ca * 32 + lq;
      union {
        unsigned u[4];
        bf16x8 v;
      } ww;
#pragma unroll
      for (int jj = 0; jj < 4; ++jj)
        ww.u[jj] = cvtpk_bf16(wp[(2 * jj) * 64], wp[(2 * jj + 1) * 64]);
      w1f[ca][kc] = ww.v;
    }

  bf16x8 w2f[2][4];
#pragma unroll
  for (int nb = 0; nb < 2; ++nb)
#pragma unroll
    for (int kc = 0; kc < 4; ++kc) {
      const float* wp = W2 + (size_t)(kc * 16 + hi * 8) * 64 + nb * 32 + lq;
      union {
        unsigned u[4];
        bf16x8 v;
      } ww;
#pragma unroll
      for (int jj = 0; jj < 4; ++jj)
        ww.u[jj] = cvtpk_bf16(wp[(2 * jj) * 64], wp[(2 * jj + 1) * 64]);
      w2f[nb][kc] = ww.v;
    }

  float b1r[2][16], b2r[2][16];
#pragma unroll
  for (int ca = 0; ca < 2; ++ca)
#pragma unroll
    for (int r = 0; r < 16; ++r) {
      b1r[ca][r] = b1[ca * 32 + (r & 3) + 8 * (r >> 2) + 4 * hi];
      b2r[ca][r] = b2[ca * 32 + (r & 3) + 8 * (r >> 2) + 4 * hi];
    }

  for (int chunk = 0; chunk < 2; ++chunk) {
    const int s0w = blockIdx.x * 256 + chunk * 128 + w * 32;

    const float* xrow = x + (((size_t)b * S_ + s0w + lq) * H_ + h) * DK_;
    bf16x8 xf[4];
#pragma unroll
    for (int kc = 0; kc < 4; ++kc) {
      float4 f0 = *(const float4*)(xrow + kc * 16 + hi * 8);
      float4 f1 = *(const float4*)(xrow + kc * 16 + hi * 8 + 4);
      union {
        unsigned u[4];
        bf16x8 v;
      } xx;
      xx.u[0] = cvtpk_bf16(f0.x, f0.y);
      xx.u[1] = cvtpk_bf16(f0.z, f0.w);
      xx.u[2] = cvtpk_bf16(f1.x, f1.y);
      xx.u[3] = cvtpk_bf16(f1.z, f1.w);
      xf[kc] = xx.v;
    }

    f32x16 acc1[2];
#pragma unroll
    for (int ca = 0; ca < 2; ++ca)
#pragma unroll
      for (int r = 0; r < 16; ++r) acc1[ca][r] = b1r[ca][r];
#pragma unroll
    for (int kc = 0; kc < 4; ++kc) {
      acc1[0] = __builtin_amdgcn_mfma_f32_32x32x16_bf16(w1f[0][kc], xf[kc], acc1[0], 0, 0, 0);
      acc1[1] = __builtin_amdgcn_mfma_f32_32x32x16_bf16(w1f[1][kc], xf[kc], acc1[1], 0, 0, 0);
    }

    float t0[16], t1[16];
#pragma unroll
    for (int r = 0; r < 16; ++r) {
      t0[r] = tanh_fast(acc1[0][r]);
      t1[r] = tanh_fast(acc1[1][r]);
    }

    bf16x8 af[4];
    af[0] = make_pa8(&t0[0], hi);
    af[1] = make_pa8(&t0[8], hi);
    af[2] = make_pa8(&t1[0], hi);
    af[3] = make_pa8(&t1[8], hi);

    f32x16 acc2[2];
#pragma unroll
    for (int nb = 0; nb < 2; ++nb)
#pragma unroll
      for (int r = 0; r < 16; ++r) acc2[nb][r] = b2r[nb][r];
#pragma unroll
    for (int kc = 0; kc < 4; ++kc) {
      acc2[0] = __builtin_amdgcn_mfma_f32_32x32x16_bf16(af[kc], w2f[0][kc], acc2[0], 0, 0, 0);
      acc2[1] = __builtin_amdgcn_mfma_f32_32x32x16_bf16(af[kc], w2f[1][kc], acc2[1], 0, 0, 0);
    }

    if (!vmode) {
#pragma unroll
      for (int nb = 0; nb < 2; ++nb)
#pragma unroll
        for (int r = 0; r < 16; ++r) {
          const int s = s0w + (r & 3) + 8 * (r >> 2) + 4 * hi;
          outp[((size_t)bh * S_ + s) * DK_ + nb * 32 + lq] =
              f2bf(acc2[nb][r] * scale);
        }
    } else {
#pragma unroll
      for (int nb = 0; nb < 2; ++nb) {
        float yv[16];
#pragma unroll
        for (int r = 0; r < 16; ++r) yv[r] = acc2[nb][r];
        const size_t rowb = ((size_t)bh * DK_ + nb * 32 + lq) * S_;
        *(bf16x8*)(outp + rowb + s0w + hi * 8) = make_pa8(&yv[0], hi);
        *(bf16x8*)(outp + rowb + s0w + 16 + hi * 8) = make_pa8(&yv[8], hi);
      }
    }
  }
}

// ---------------------------------------------------------------------------
// Kernel 2: MFMA flash attention (FROZEN, r19): QBLK=256, 8 q-group waves,
// exp2-direct softmax, l via ones-B MFMA, 3-buf depth-2 counted-vmcnt
// staging. grid (32 bh, 8 q-blocks), block 512, 48KB LDS.
// ---------------------------------------------------------------------------
__global__ __launch_bounds__(512, 2) void attn_kernel(
    const unsigned short* __restrict__ qhb,
    const unsigned short* __restrict__ khb,
    const unsigned short* __restrict__ vtb,
    unsigned short* __restrict__ ctxb) {
  __shared__ __align__(16) unsigned short kvbuf[3][2][64 * 64];  // 3-buf K/V

  const int tid = threadIdx.x;
  const int w = tid >> 6;  // 0..7 = q-group
  const int l = tid & 63;
  const int lq = l & 31;
  const int hi = l >> 5;
  const int bh = blockIdx.x;
  const int b = bh >> 4, h = bh & 15;
  const int q0 = blockIdx.y * 256 + w * 32;

  const unsigned short* qp = qhb + ((size_t)bh * S_ + q0 + lq) * DK_ + hi * 8;
  bf16x8 qf[4];
#pragma unroll
  for (int kc = 0; kc < 4; ++kc) qf[kc] = *(const bf16x8*)(qp + kc * 16);

  f32x16 o0 = {}, o1 = {};
  f32x16 lacc = {};

  union {
    unsigned u[4];
    bf16x8 v;
  } onesu;
  onesu.u[0] = 0x3F803F80u;
  onesu.u[1] = 0x3F803F80u;
  onesu.u[2] = 0x3F803F80u;
  onesu.u[3] = 0x3F803F80u;
  const bf16x8 ones = onesu.v;

  const unsigned short* kgbase = khb + (size_t)bh * S_ * DK_;
  const unsigned short* vgbase = vtb + (size_t)bh * DK_ * S_;
  const int srow = tid >> 3;
  const int sl8 = ((tid & 7) ^ (srow & 7)) * 8;

  const unsigned short* kp = kgbase + (size_t)srow * DK_ + sl8;
  const unsigned short* vp = vgbase + (size_t)srow * S_ + sl8;

#define STAGE(BUF)                                                            \
  {                                                                           \
    load16_lds(kp, (char*)kvbuf[BUF][0] + w * 1024);                          \
    load16_lds(vp, (char*)kvbuf[BUF][1] + w * 1024);                          \
    kp += 64 * DK_;                                                           \
    vp += 64;                                                                 \
  }

  STAGE(0)
  STAGE(1)

  for (int t = 0; t < 32; ++t) {
    if (t < 31) {
      asm volatile("s_waitcnt vmcnt(2)" ::: "memory");
    } else {
      asm volatile("s_waitcnt vmcnt(0)" ::: "memory");
    }
    __builtin_amdgcn_sched_barrier(0);
    __builtin_amdgcn_s_barrier();
    __builtin_amdgcn_sched_barrier(0);

    const int cur = t % 3;
    const char* ksP = (const char*)kvbuf[cur][0];
    const char* vsP = (const char*)kvbuf[cur][1];
    if (t < 30) STAGE((t + 2) % 3)

    f32x16 s0a = {}, s0b = {};
    __builtin_amdgcn_s_setprio(1);
#pragma unroll
    for (int kc = 0; kc < 4; ++kc) {
      const int so = ((kc * 2 + hi) ^ (lq & 7)) << 4;
      bf16x8 ka = *(const bf16x8*)(ksP + lq * 128 + so);
      bf16x8 kb = *(const bf16x8*)(ksP + (32 + lq) * 128 + so);
      s0a = __builtin_amdgcn_mfma_f32_32x32x16_bf16(ka, qf[kc], s0a, 0, 0, 0);
      s0b = __builtin_amdgcn_mfma_f32_32x32x16_bf16(kb, qf[kc], s0b, 0, 0, 0);
    }
    __builtin_amdgcn_s_setprio(0);

#pragma unroll
    for (int i = 0; i < 16; ++i) s0a[i] = exp2f(s0a[i]);
#pragma unroll
    for (int i = 0; i < 16; ++i) s0b[i] = exp2f(s0b[i]);

    float pv[8];
    __builtin_amdgcn_s_setprio(1);
#pragma unroll
    for (int kc = 0; kc < 4; ++kc) {
#pragma unroll
      for (int j = 0; j < 8; ++j) pv[j] = (kc < 2) ? s0a[(kc & 1) * 8 + j]
                                                   : s0b[(kc & 1) * 8 + j];
      bf16x8 pav = make_pa8(pv, hi);
      const int slot = kc * 2 + hi;
      bf16x8 v0 = *(const bf16x8*)(vsP + lq * 128 + ((slot ^ (lq & 7)) << 4));
      bf16x8 v1 = *(const bf16x8*)(vsP + (32 + lq) * 128 + ((slot ^ (lq & 7)) << 4));
      o0 = __builtin_amdgcn_mfma_f32_32x32x16_bf16(pav, v0, o0, 0, 0, 0);
      o1 = __builtin_amdgcn_mfma_f32_32x32x16_bf16(pav, v1, o1, 0, 0, 0);
      lacc = __builtin_amdgcn_mfma_f32_32x32x16_bf16(pav, ones, lacc, 0, 0, 0);
    }
    __builtin_amdgcn_s_setprio(0);
  }
#undef STAGE

#pragma unroll
  for (int r = 0; r < 16; ++r) {
    const int crow = ((r & 3) + 8 * (r >> 2)) + 4 * hi;
    const float li = 1.0f / lacc[r];
    const int qg = q0 + crow;
    const size_t base = ((size_t)b * S_ + qg) * D_ + h * DK_;
    ctxb[base + lq] = f2bf(o0[r] * li);
    ctxb[base + 32 + lq] = f2bf(o1[r] * li);
  }
}

// ---------------------------------------------------------------------------
// Kernel 3: out[4096,1024] = ctx_bf16 @ WoT^T + bo (FROZEN, r17).
// ---------------------------------------------------------------------------
__global__ __launch_bounds__(256) void out_gemm_mfma(
    const unsigned short* __restrict__ A,
    const unsigned short* __restrict__ BT,
    const float* __restrict__ bo, float* __restrict__ C) {
  __shared__ __align__(16) unsigned short As[2][128 * 64];
  __shared__ __align__(16) unsigned short Bs[2][64 * 64];

  const int tid = threadIdx.x;
  const int w = tid >> 6, l = tid & 63;
  const int ll = l & 15, lg = l >> 4;
  const int m0 = blockIdx.y * 128, n0 = blockIdx.x * 64;

  const int srow = l >> 3;
  const int sl8 = ((l & 7) ^ srow) * 8;

  f32x4 acc[2][4];
#pragma unroll
  for (int mt = 0; mt < 2; ++mt)
#pragma unroll
    for (int nt = 0; nt < 4; ++nt) acc[mt][nt] = (f32x4){0.f, 0.f, 0.f, 0.f};

#define STAGE_G(BUF, KT)                                                      \
  {                                                                           \
    const int k0e = (KT)*64;                                                  \
    _Pragma("unroll") for (int j = 0; j < 4; ++j) {                           \
      const int rowa = (w * 4 + j) * 8 + srow;                                \
      load16_lds(A + (size_t)(m0 + rowa) * D_ + k0e + sl8,                    \
                 (char*)As[BUF] + (w * 4 + j) * 1024);                        \
    }                                                                         \
    _Pragma("unroll") for (int j = 0; j < 2; ++j) {                           \
      const int rowb = (w * 2 + j) * 8 + srow;                                \
      load16_lds(BT + (size_t)(n0 + rowb) * D_ + k0e + sl8,                   \
                 (char*)Bs[BUF] + (w * 2 + j) * 1024);                        \
    }                                                                         \
  }

  STAGE_G(0, 0)
  __syncthreads();

  for (int kt = 0; kt < 16; ++kt) {
    const int cur = kt & 1;
    if (kt < 15) STAGE_G(cur ^ 1, kt + 1)

#pragma unroll
    for (int half = 0; half < 2; ++half) {
      bf16x8 af[2], bfr[4];
#pragma unroll
      for (int mt = 0; mt < 2; ++mt) {
        const int row = w * 32 + mt * 16 + ll;
        af[mt] = *(const bf16x8*)((const char*)As[cur] + row * 128 +
                                  (((half * 4 + lg) ^ (row & 7)) << 4));
      }
#pragma unroll
      for (int nt = 0; nt < 4; ++nt) {
        const int rowb = nt * 16 + ll;
        bfr[nt] = *(const bf16x8*)((const char*)Bs[cur] + rowb * 128 +
                                   (((half * 4 + lg) ^ (rowb & 7)) << 4));
      }
      __builtin_amdgcn_s_setprio(1);
#pragma unroll
      for (int mt = 0; mt < 2; ++mt)
#pragma unroll
        for (int nt = 0; nt < 4; ++nt)
          acc[mt][nt] = __builtin_amdgcn_mfma_f32_16x16x32_bf16(
              af[mt], bfr[nt], acc[mt][nt], 0, 0, 0);
      __builtin_amdgcn_s_setprio(0);
    }

    __syncthreads();
  }
#undef STAGE_G

#pragma unroll
  for (int nt = 0; nt < 4; ++nt) {
    const int col = n0 + nt * 16 + ll;
    const float bv = bo[col];
#pragma unroll
    for (int mt = 0; mt < 2; ++mt) {
      const int row0 = m0 + w * 32 + mt * 16 + lg * 4;
#pragma unroll
      for (int r = 0; r < 4; ++r)
        C[(size_t)(row0 + r) * D_ + col] = acc[mt][nt][r] + bv;
    }
  }
}

// ---------------------------------------------------------------------------
extern "C" void kernel_launch(void* const* d_in, const int* in_sizes, int n_in,
                              void* d_out, int out_size, void* d_ws,
                              size_t ws_size, hipStream_t stream) {
  const float* q = (const float*)d_in[0];
  const float* k = (const float*)d_in[1];
  const float* v = (const float*)d_in[2];
  const float* Wq1 = (const float*)d_in[3];
  const float* bq1 = (const float*)d_in[4];
  const float* Wq2 = (const float*)d_in[5];
  const float* bq2 = (const float*)d_in[6];
  const float* Wk1 = (const float*)d_in[7];
  const float* bk1 = (const float*)d_in[8];
  const float* Wk2 = (const float*)d_in[9];
  const float* bk2 = (const float*)d_in[10];
  const float* Wv1 = (const float*)d_in[11];
  const float* bv1 = (const float*)d_in[12];
  const float* Wv2 = (const float*)d_in[13];
  const float* bv2 = (const float*)d_in[14];
  const float* Wo = (const float*)d_in[15];
  const float* bo = (const float*)d_in[16];
  float* out = (float*)d_out;

  const size_t TEN = (size_t)B_ * H_ * S_ * DK_;  // 4,194,304 elements
  char* ws = (char*)d_ws;
  unsigned short* qhb = (unsigned short*)ws;              // bf16 [BH,S,DK]
  unsigned short* khb = (unsigned short*)(ws + TEN * 2);  // bf16 [BH,S,DK]
  unsigned short* vtb = (unsigned short*)(ws + TEN * 4);  // bf16 [BH,DK,S]
  unsigned short* ctxb = (unsigned short*)(ws + TEN * 6); // bf16 [B,S,D]
  unsigned short* wot = (unsigned short*)(ws + TEN * 8);  // bf16 [N,K] = Wo^T

  const float cs = 0.125f * 1.44269504088896340736f;  // 1/sqrt(64) * log2(e)
  quantum_fused<<<dim3(8, 32, 4), 256, 0, stream>>>(
      q, k, v, Wq1, bq1, Wq2, bq2, Wk1, bk1, Wk2, bk2, Wv1, bv1, Wv2, bv2,
      Wo, wot, qhb, khb, vtb, cs);

  attn_kernel<<<dim3(32, 8), 512, 0, stream>>>(qhb, khb, vtb, ctxb);

  out_gemm_mfma<<<dim3(16, 32), 256, 0, stream>>>(ctxb, wot, bo, out);
}